// Round 10
// baseline (162.436 us; speedup 1.0000x reference)
//
#include <hip/hip_runtime.h>
#include <hip/hip_bf16.h>

#define Bq 16
#define Lq 4096
#define Dq 256
#define Nq 64
#define Oq 256
#define Tq 64
#define Cq (Lq / Tq)   // 64 chunks

typedef __attribute__((ext_vector_type(4))) float f32x4;
typedef __attribute__((ext_vector_type(8))) short bf16x8;
typedef __attribute__((ext_vector_type(4))) unsigned short u16x4;

// fast softplus: matches max(x,0)+log1p(exp(-|x|)) to ~1e-6 rel
__device__ __forceinline__ float softplus_f(float v) {
    const float e = __expf(-fabsf(v));
    return fmaxf(v, 0.0f) + __logf(1.0f + e);
}

__device__ __forceinline__ unsigned short f2bf(float f) {
    unsigned int u = __builtin_bit_cast(unsigned int, f);
    unsigned int r = (u + 0x7fffu + ((u >> 16) & 1u)) >> 16;
    return (unsigned short)r;
}

// ---------------------------------------------------------------------------
// Kernel 0: one-time conversion of [sel_W; delta_W; Bm] -> bf16 [192][256]
// ---------------------------------------------------------------------------
__global__ __launch_bounds__(256) void prep_w_k(
    const float* __restrict__ sel_W,
    const float* __restrict__ delta_W,
    const float* __restrict__ Bm,
    unsigned short* __restrict__ wbf)
{
    const int idx = blockIdx.x * 256 + threadIdx.x;  // float4 index, 12288 total
    const int row = idx >> 6;                        // 0..191
    const int c4  = (idx & 63) * 4;
    const float* src = (row < 64)  ? (sel_W   + (size_t)row * 256 + c4)
                     : (row < 128) ? (delta_W + (size_t)(row - 64) * 256 + c4)
                                   : (Bm      + (size_t)(row - 128) * 256 + c4);
    f32x4 v = *(const f32x4*)src;
    u16x4 pk;
    #pragma unroll
    for (int j = 0; j < 4; ++j) pk[j] = f2bf(v[j]);
    *(u16x4*)(wbf + (size_t)row * 256 + c4) = pk;
}

// ---------------------------------------------------------------------------
// Kernel 1: per (b, chunk of 64 tokens):
//   conv1d -> xc(bf16, LDS swizzled, 32 KiB); W frags loaded from global bf16 W
//   in batches of 12 (48 VGPR in flight, counted vmcnt) -> 96 MFMA ->
//   elementwise (native exp/log) -> ordered (P,S) chunk summary.
// VGPR target ~120 (cap 128 via launch_bounds) -> 4 blocks/CU.
// ---------------------------------------------------------------------------
__global__ __launch_bounds__(256, 4) void mamba_chunk_k(
    const float* __restrict__ x,
    const unsigned short* __restrict__ wbf,   // [192][256] bf16
    const float* __restrict__ sel_b,
    const float* __restrict__ selection_bias,
    const float* __restrict__ A_log,
    const float* __restrict__ delta_b,
    const float* __restrict__ conv_w,
    const float* __restrict__ conv_b,
    float* __restrict__ wsP,
    float* __restrict__ wsS)
{
    __shared__ char xc_base[Tq * 512];   // 64 rows x 512 B (bf16, swizzled)

    const int tid = threadIdx.x;
    const int b   = blockIdx.x >> 6;
    const int c   = blockIdx.x & 63;
    const int l0  = c * Tq;

    const int wv   = tid >> 6;
    const int lane = tid & 63;
    const int lr   = lane & 15;
    const int lg   = lane >> 4;

    // hoist per-lane scan scalars early (latency hides under conv+GEMM)
    const int   n   = wv * 16 + lr;
    const float Alg = A_log[n];
    const float sbc = sel_b[n] + selection_bias[n];
    const float dbv = delta_b[n];

    // ---- Phase A: depthwise conv -> bf16 xc tile (16 rows per wave) ----
    const int d0 = lane * 4;

    float cw0[4], cw1[4], cw2[4], cbv[4];
    #pragma unroll
    for (int j = 0; j < 4; ++j) {
        cw0[j] = conv_w[(d0 + j) * 3 + 0];
        cw1[j] = conv_w[(d0 + j) * 3 + 1];
        cw2[j] = conv_w[(d0 + j) * 3 + 2];
        cbv[j] = conv_b[d0 + j];
    }

    const int tb = wv * 16;
    const float* rp = x + ((long)b * Lq + (l0 + tb)) * Dq + d0;
    f32x4 xm1 = (f32x4){0.f, 0.f, 0.f, 0.f};
    if (l0 + tb - 1 >= 0) xm1 = *(const f32x4*)(rp - Dq);
    f32x4 xcur = *(const f32x4*)rp;

    #pragma unroll
    for (int it = 0; it < 16; ++it) {
        const int l = l0 + tb + it;
        f32x4 xp1 = (f32x4){0.f, 0.f, 0.f, 0.f};
        if (l + 1 < Lq) xp1 = *(const f32x4*)(rp + (size_t)(it + 1) * Dq);
        u16x4 pk;
        #pragma unroll
        for (int j = 0; j < 4; ++j) {
            float v = fmaf(cw0[j], xm1[j], fmaf(cw1[j], xcur[j], fmaf(cw2[j], xp1[j], cbv[j])));
            pk[j] = f2bf(v);
        }
        const int row = tb + it;
        *(u16x4*)(xc_base + row * 512 + ((d0 * 2) ^ ((row & 7) << 4))) = pk;
        xm1 = xcur; xcur = xp1;
    }

    // ---- Phase B: GEMM. wave wv owns n in [16*wv, 16*wv+16) for all 3 mats ----
    const unsigned short* wrow = wbf + (size_t)n * 256 + lg * 8;

    // issue first W batch (12 loads, 48 VGPR) BEFORE the barrier: independent of LDS
    bf16x8 bfr[4][3];
    #pragma unroll
    for (int kk = 0; kk < 4; ++kk)
        #pragma unroll
        for (int j = 0; j < 3; ++j)
            bfr[kk][j] = *(const bf16x8*)(wrow + (size_t)j * 16384 + kk * 32);

    __syncthreads();

    f32x4 acc[4][3];
    #pragma unroll
    for (int m = 0; m < 4; ++m)
        #pragma unroll
        for (int j = 0; j < 3; ++j)
            acc[m][j] = (f32x4){0.f, 0.f, 0.f, 0.f};

    #pragma unroll
    for (int g = 0; g < 2; ++g) {
        if (g == 1) {
            // second W batch; counted vmcnt lets these 12 loads overlap compute below
            #pragma unroll
            for (int kk = 0; kk < 4; ++kk)
                #pragma unroll
                for (int j = 0; j < 3; ++j)
                    bfr[kk][j] = *(const bf16x8*)(wrow + (size_t)j * 16384 + (4 + kk) * 32);
        }
        #pragma unroll
        for (int kk = 0; kk < 4; ++kk) {
            const int cb = (g * 4 + kk) * 64 + lg * 16;
            #pragma unroll
            for (int m = 0; m < 4; ++m) {
                const int row = m * 16 + lr;
                bf16x8 af = *(const bf16x8*)(xc_base + row * 512 + (cb ^ ((row & 7) << 4)));
                #pragma unroll
                for (int j = 0; j < 3; ++j)
                    acc[m][j] = __builtin_amdgcn_mfma_f32_16x16x32_bf16(af, bfr[kk][j], acc[m][j], 0, 0, 0);
            }
        }
    }

    // ---- Phase C: elementwise (native transcendentals) + ordered (P,S) scan ----
    const float Av = -__expf(Alg);
    const float rD = 1.0f / (Av + 1e-8f);

    float Ptot = 1.0f, Stot = 0.0f;
    #pragma unroll
    for (int m = 0; m < 4; ++m) {
        float P = 1.0f, S = 0.0f;
        #pragma unroll
        for (int r = 0; r < 4; ++r) {
            const float sel = softplus_f(acc[m][0][r] + sbc);
            const float dl  = softplus_f(acc[m][1][r] + dbv);
            const float a   = __expf(dl * Av);
            const float bx  = (a - 1.0f) * rD * sel * acc[m][2][r];
            P *= a;
            S = fmaf(S, a, bx);
        }
        float Po = __shfl_xor(P, 16);
        float So = __shfl_xor(S, 16);
        if ((lg & 1) == 0) { S = fmaf(S, Po, So); P = P * Po; }
        else               { S = fmaf(So, P, S);  P = Po * P; }
        Po = __shfl_xor(P, 32);
        So = __shfl_xor(S, 32);
        if ((lg & 2) == 0) { S = fmaf(S, Po, So); P = P * Po; }
        else               { S = fmaf(So, P, S);  P = Po * P; }
        Stot = fmaf(Stot, P, S);
        Ptot *= P;
    }

    if (lg == 0) {
        const int o = (b * Cq + c) * Nq + n;
        wsP[o] = Ptot;
        wsS[o] = Stot;
    }
}

// ---------------------------------------------------------------------------
// Kernel 2: combine chunk summaries over time, then y = s@Cm^T + xc_last@Dm^T
// ---------------------------------------------------------------------------
__global__ __launch_bounds__(256) void mamba_final_k(
    const float* __restrict__ x,
    const float* __restrict__ conv_w,
    const float* __restrict__ conv_b,
    const float* __restrict__ Cm,
    const float* __restrict__ Dm,
    const float* __restrict__ wsP,
    const float* __restrict__ wsS,
    float* __restrict__ out)
{
    const int b   = blockIdx.x;
    const int tid = threadIdx.x;
    __shared__ float s_sh[Nq];
    __shared__ float xl_sh[Dq];

    {
        const int n   = tid >> 2;
        const int seg = tid & 3;
        float P = 1.0f, S = 0.0f;
        #pragma unroll
        for (int i = 0; i < 16; ++i) {
            const int c = seg * 16 + i;
            const float p  = wsP[(b * Cq + c) * Nq + n];
            const float s2 = wsS[(b * Cq + c) * Nq + n];
            S = fmaf(S, p, s2);
            P *= p;
        }
        float Po = __shfl_xor(P, 1);
        float So = __shfl_xor(S, 1);
        if ((seg & 1) == 0) { S = fmaf(S, Po, So); P = P * Po; }
        else                { S = fmaf(So, P, S);  P = Po * P; }
        Po = __shfl_xor(P, 2);
        So = __shfl_xor(S, 2);
        if ((seg & 2) == 0) { S = fmaf(S, Po, So); P = P * Po; }
        else                { S = fmaf(So, P, S);  P = Po * P; }
        if (seg == 0) s_sh[n] = S;
    }
    {
        const int d = tid;
        const float xm1 = x[((long)b * Lq + (Lq - 2)) * Dq + d];
        const float x0  = x[((long)b * Lq + (Lq - 1)) * Dq + d];
        xl_sh[d] = fmaf(conv_w[d * 3 + 0], xm1, fmaf(conv_w[d * 3 + 1], x0, conv_b[d]));
    }
    __syncthreads();

    const int o = tid;
    float accv = 0.0f;
    #pragma unroll 8
    for (int n = 0; n < Nq; ++n) accv = fmaf(s_sh[n], Cm[o * Nq + n], accv);
    #pragma unroll 8
    for (int d = 0; d < Dq; ++d) accv = fmaf(xl_sh[d], Dm[o * Dq + d], accv);
    out[b * Oq + o] = accv;
}

extern "C" void kernel_launch(void* const* d_in, const int* in_sizes, int n_in,
                              void* d_out, int out_size, void* d_ws, size_t ws_size,
                              hipStream_t stream)
{
    const float* x       = (const float*)d_in[0];
    const float* sel_W   = (const float*)d_in[1];
    const float* sel_b   = (const float*)d_in[2];
    const float* sel_bias= (const float*)d_in[3];
    const float* A_log   = (const float*)d_in[4];
    const float* Bm      = (const float*)d_in[5];
    const float* Cm      = (const float*)d_in[6];
    const float* Dm      = (const float*)d_in[7];
    const float* delta_W = (const float*)d_in[8];
    const float* delta_b = (const float*)d_in[9];
    const float* conv_w  = (const float*)d_in[10];
    const float* conv_b  = (const float*)d_in[11];
    float* out = (float*)d_out;

    float* wsP = (float*)d_ws;                               // 256 KB
    float* wsS = wsP + (size_t)Bq * Cq * Nq;                 // 256 KB
    unsigned short* wbf = (unsigned short*)(wsS + (size_t)Bq * Cq * Nq);  // 96 KB bf16

    prep_w_k<<<dim3(48), dim3(256), 0, stream>>>(sel_W, delta_W, Bm, wbf);
    mamba_chunk_k<<<dim3(Bq * Cq), dim3(256), 0, stream>>>(
        x, wbf, sel_b, sel_bias, A_log, delta_b, conv_w, conv_b, wsP, wsS);
    mamba_final_k<<<dim3(Bq), dim3(256), 0, stream>>>(
        x, conv_w, conv_b, Cm, Dm, wsP, wsS, out);
}

// Round 11
// 137.159 us; speedup vs baseline: 1.1843x; 1.1843x over previous
//
#include <hip/hip_runtime.h>
#include <hip/hip_bf16.h>

#define Bq 16
#define Lq 4096
#define Dq 256
#define Nq 64
#define Oq 256
#define Tq 64
#define Cq (Lq / Tq)   // 64 chunks

typedef __attribute__((ext_vector_type(4))) float f32x4;
typedef __attribute__((ext_vector_type(8))) short bf16x8;
typedef __attribute__((ext_vector_type(4))) unsigned short u16x4;

// fast softplus: matches max(x,0)+log1p(exp(-|x|)) to ~1e-6 rel
__device__ __forceinline__ float softplus_f(float v) {
    const float e = __expf(-fabsf(v));
    return fmaxf(v, 0.0f) + __logf(1.0f + e);
}

__device__ __forceinline__ unsigned short f2bf(float f) {
    unsigned int u = __builtin_bit_cast(unsigned int, f);
    unsigned int r = (u + 0x7fffu + ((u >> 16) & 1u)) >> 16;
    return (unsigned short)r;
}

// ---------------------------------------------------------------------------
// Kernel 0: one-time conversion of [sel_W; delta_W; Bm] -> bf16 [192][256]
// ---------------------------------------------------------------------------
__global__ __launch_bounds__(256) void prep_w_k(
    const float* __restrict__ sel_W,
    const float* __restrict__ delta_W,
    const float* __restrict__ Bm,
    unsigned short* __restrict__ wbf)
{
    const int idx = blockIdx.x * 256 + threadIdx.x;  // float4 index, 12288 total
    const int row = idx >> 6;                        // 0..191
    const int c4  = (idx & 63) * 4;
    const float* src = (row < 64)  ? (sel_W   + (size_t)row * 256 + c4)
                     : (row < 128) ? (delta_W + (size_t)(row - 64) * 256 + c4)
                                   : (Bm      + (size_t)(row - 128) * 256 + c4);
    f32x4 v = *(const f32x4*)src;
    u16x4 pk;
    #pragma unroll
    for (int j = 0; j < 4; ++j) pk[j] = f2bf(v[j]);
    *(u16x4*)(wbf + (size_t)row * 256 + c4) = pk;
}

// ---------------------------------------------------------------------------
// Kernel 1: per (b, chunk of 64 tokens):
//   conv1d (two 8-row halves, 10 x-loads batched up front) -> xc bf16 LDS
//   (swizzled, 32 KiB); W frags from global bf16 W, 3-deep rotating prefetch
//   -> 96 MFMA -> elementwise (native exp/log) -> ordered (P,S) summary.
// grid 1024 = 4 blocks/CU -> 16 waves/CU cap; VGPR budget 128 is free to use.
// ---------------------------------------------------------------------------
__global__ __launch_bounds__(256, 4) void mamba_chunk_k(
    const float* __restrict__ x,
    const unsigned short* __restrict__ wbf,   // [192][256] bf16
    const float* __restrict__ sel_b,
    const float* __restrict__ selection_bias,
    const float* __restrict__ A_log,
    const float* __restrict__ delta_b,
    const float* __restrict__ conv_w,
    const float* __restrict__ conv_b,
    float* __restrict__ wsP,
    float* __restrict__ wsS)
{
    __shared__ char xc_base[Tq * 512];   // 64 rows x 512 B (bf16, swizzled)

    const int tid = threadIdx.x;
    const int b   = blockIdx.x >> 6;
    const int c   = blockIdx.x & 63;
    const int l0  = c * Tq;

    const int wv   = tid >> 6;
    const int lane = tid & 63;
    const int lr   = lane & 15;
    const int lg   = lane >> 4;

    // per-lane scan scalars (latency hides under conv+GEMM)
    const int   n   = wv * 16 + lr;
    const float Alg = A_log[n];
    const float sbc = sel_b[n] + selection_bias[n];
    const float dbv = delta_b[n];

    // W row base for this lane; prefetch kk=0 fragments before conv (L2 latency
    // hides under the whole conv phase)
    const unsigned short* wrow = wbf + (size_t)n * 256 + lg * 8;
    bf16x8 bfr[3];
    #pragma unroll
    for (int j = 0; j < 3; ++j)
        bfr[j] = *(const bf16x8*)(wrow + (size_t)j * 16384);

    // ---- Phase A: depthwise conv -> bf16 xc tile (16 rows/wave, 2 halves) ----
    const int d0 = lane * 4;

    float cw0[4], cw1[4], cw2[4], cbv[4];
    #pragma unroll
    for (int j = 0; j < 4; ++j) {
        cw0[j] = conv_w[(d0 + j) * 3 + 0];
        cw1[j] = conv_w[(d0 + j) * 3 + 1];
        cw2[j] = conv_w[(d0 + j) * 3 + 2];
        cbv[j] = conv_b[d0 + j];
    }

    const int tb = wv * 16;
    #pragma unroll
    for (int h = 0; h < 2; ++h) {
        // rows tb+8h .. tb+8h+7 need x rows g0 .. g0+9 where g0 = l0+tb+8h-1
        const int g0 = l0 + tb + h * 8 - 1;
        f32x4 xr[10];
        #pragma unroll
        for (int i = 0; i < 10; ++i) {
            const int g = g0 + i;
            xr[i] = (f32x4){0.f, 0.f, 0.f, 0.f};
            if (g >= 0 && g < Lq)
                xr[i] = *(const f32x4*)(x + ((long)b * Lq + g) * Dq + d0);
        }
        #pragma unroll
        for (int it = 0; it < 8; ++it) {
            const int row = tb + h * 8 + it;
            u16x4 pk;
            #pragma unroll
            for (int j = 0; j < 4; ++j) {
                float v = fmaf(cw0[j], xr[it][j],
                          fmaf(cw1[j], xr[it + 1][j],
                          fmaf(cw2[j], xr[it + 2][j], cbv[j])));
                pk[j] = f2bf(v);
            }
            *(u16x4*)(xc_base + row * 512 + ((d0 * 2) ^ ((row & 7) << 4))) = pk;
        }
    }
    __syncthreads();

    // ---- Phase B: GEMM with 3-deep rotating W prefetch ----
    f32x4 acc[4][3];
    #pragma unroll
    for (int m = 0; m < 4; ++m)
        #pragma unroll
        for (int j = 0; j < 3; ++j)
            acc[m][j] = (f32x4){0.f, 0.f, 0.f, 0.f};

    #pragma unroll
    for (int kk = 0; kk < 8; ++kk) {
        bf16x8 cur[3];
        #pragma unroll
        for (int j = 0; j < 3; ++j) cur[j] = bfr[j];
        if (kk < 7) {
            #pragma unroll
            for (int j = 0; j < 3; ++j)
                bfr[j] = *(const bf16x8*)(wrow + (size_t)j * 16384 + (kk + 1) * 32);
        }
        const int cb = kk * 64 + lg * 16;
        #pragma unroll
        for (int m = 0; m < 4; ++m) {
            const int row = m * 16 + lr;
            bf16x8 af = *(const bf16x8*)(xc_base + row * 512 + (cb ^ ((row & 7) << 4)));
            #pragma unroll
            for (int j = 0; j < 3; ++j)
                acc[m][j] = __builtin_amdgcn_mfma_f32_16x16x32_bf16(af, cur[j], acc[m][j], 0, 0, 0);
        }
    }

    // ---- Phase C: elementwise (native transcendentals) + ordered (P,S) scan ----
    const float Av = -__expf(Alg);
    const float rD = 1.0f / (Av + 1e-8f);

    float Ptot = 1.0f, Stot = 0.0f;
    #pragma unroll
    for (int m = 0; m < 4; ++m) {
        float P = 1.0f, S = 0.0f;
        #pragma unroll
        for (int r = 0; r < 4; ++r) {
            const float sel = softplus_f(acc[m][0][r] + sbc);
            const float dl  = softplus_f(acc[m][1][r] + dbv);
            const float a   = __expf(dl * Av);
            const float bx  = (a - 1.0f) * rD * sel * acc[m][2][r];
            P *= a;
            S = fmaf(S, a, bx);
        }
        float Po = __shfl_xor(P, 16);
        float So = __shfl_xor(S, 16);
        if ((lg & 1) == 0) { S = fmaf(S, Po, So); P = P * Po; }
        else               { S = fmaf(So, P, S);  P = Po * P; }
        Po = __shfl_xor(P, 32);
        So = __shfl_xor(S, 32);
        if ((lg & 2) == 0) { S = fmaf(S, Po, So); P = P * Po; }
        else               { S = fmaf(So, P, S);  P = Po * P; }
        Stot = fmaf(Stot, P, S);
        Ptot *= P;
    }

    if (lg == 0) {
        const int o = (b * Cq + c) * Nq + n;
        wsP[o] = Ptot;
        wsS[o] = Stot;
    }
}

// ---------------------------------------------------------------------------
// Kernel 2: combine chunk summaries over time, then y = s@Cm^T + xc_last@Dm^T
// ---------------------------------------------------------------------------
__global__ __launch_bounds__(256) void mamba_final_k(
    const float* __restrict__ x,
    const float* __restrict__ conv_w,
    const float* __restrict__ conv_b,
    const float* __restrict__ Cm,
    const float* __restrict__ Dm,
    const float* __restrict__ wsP,
    const float* __restrict__ wsS,
    float* __restrict__ out)
{
    const int b   = blockIdx.x;
    const int tid = threadIdx.x;
    __shared__ float s_sh[Nq];
    __shared__ float xl_sh[Dq];

    {
        const int n   = tid >> 2;
        const int seg = tid & 3;
        float P = 1.0f, S = 0.0f;
        #pragma unroll
        for (int i = 0; i < 16; ++i) {
            const int c = seg * 16 + i;
            const float p  = wsP[(b * Cq + c) * Nq + n];
            const float s2 = wsS[(b * Cq + c) * Nq + n];
            S = fmaf(S, p, s2);
            P *= p;
        }
        float Po = __shfl_xor(P, 1);
        float So = __shfl_xor(S, 1);
        if ((seg & 1) == 0) { S = fmaf(S, Po, So); P = P * Po; }
        else                { S = fmaf(So, P, S);  P = Po * P; }
        Po = __shfl_xor(P, 2);
        So = __shfl_xor(S, 2);
        if ((seg & 2) == 0) { S = fmaf(S, Po, So); P = P * Po; }
        else                { S = fmaf(So, P, S);  P = Po * P; }
        if (seg == 0) s_sh[n] = S;
    }
    {
        const int d = tid;
        const float xm1 = x[((long)b * Lq + (Lq - 2)) * Dq + d];
        const float x0  = x[((long)b * Lq + (Lq - 1)) * Dq + d];
        xl_sh[d] = fmaf(conv_w[d * 3 + 0], xm1, fmaf(conv_w[d * 3 + 1], x0, conv_b[d]));
    }
    __syncthreads();

    const int o = tid;
    float accv = 0.0f;
    #pragma unroll 8
    for (int n = 0; n < Nq; ++n) accv = fmaf(s_sh[n], Cm[o * Nq + n], accv);
    #pragma unroll 8
    for (int d = 0; d < Dq; ++d) accv = fmaf(xl_sh[d], Dm[o * Dq + d], accv);
    out[b * Oq + o] = accv;
}

extern "C" void kernel_launch(void* const* d_in, const int* in_sizes, int n_in,
                              void* d_out, int out_size, void* d_ws, size_t ws_size,
                              hipStream_t stream)
{
    const float* x       = (const float*)d_in[0];
    const float* sel_W   = (const float*)d_in[1];
    const float* sel_b   = (const float*)d_in[2];
    const float* sel_bias= (const float*)d_in[3];
    const float* A_log   = (const float*)d_in[4];
    const float* Bm      = (const float*)d_in[5];
    const float* Cm      = (const float*)d_in[6];
    const float* Dm      = (const float*)d_in[7];
    const float* delta_W = (const float*)d_in[8];
    const float* delta_b = (const float*)d_in[9];
    const float* conv_w  = (const float*)d_in[10];
    const float* conv_b  = (const float*)d_in[11];
    float* out = (float*)d_out;

    float* wsP = (float*)d_ws;                               // 256 KB
    float* wsS = wsP + (size_t)Bq * Cq * Nq;                 // 256 KB
    unsigned short* wbf = (unsigned short*)(wsS + (size_t)Bq * Cq * Nq);  // 96 KB bf16

    prep_w_k<<<dim3(48), dim3(256), 0, stream>>>(sel_W, delta_W, Bm, wbf);
    mamba_chunk_k<<<dim3(Bq * Cq), dim3(256), 0, stream>>>(
        x, wbf, sel_b, sel_bias, A_log, delta_b, conv_w, conv_b, wsP, wsS);
    mamba_final_k<<<dim3(Bq), dim3(256), 0, stream>>>(
        x, conv_w, conv_b, Cm, Dm, wsP, wsS, out);
}

// Round 13
// 137.129 us; speedup vs baseline: 1.1846x; 1.0002x over previous
//
#include <hip/hip_runtime.h>
#include <hip/hip_bf16.h>

#define Bq 16
#define Lq 4096
#define Dq 256
#define Nq 64
#define Oq 256
#define Tq 64
#define Cq (Lq / Tq)   // 64 chunks

typedef __attribute__((ext_vector_type(4))) float f32x4;
typedef __attribute__((ext_vector_type(8))) short bf16x8;
typedef __attribute__((ext_vector_type(4))) unsigned short u16x4;

// fast softplus: matches max(x,0)+log1p(exp(-|x|)) to ~1e-6 rel
__device__ __forceinline__ float softplus_f(float v) {
    const float e = __expf(-fabsf(v));
    return fmaxf(v, 0.0f) + __logf(1.0f + e);
}

__device__ __forceinline__ unsigned short f2bf(float f) {
    unsigned int u = __builtin_bit_cast(unsigned int, f);
    unsigned int r = (u + 0x7fffu + ((u >> 16) & 1u)) >> 16;
    return (unsigned short)r;
}

// ---------------------------------------------------------------------------
// Kernel 0: one-time conversion of [sel_W; delta_W; Bm] -> bf16 [192][256]
// ---------------------------------------------------------------------------
__global__ __launch_bounds__(256) void prep_w_k(
    const float* __restrict__ sel_W,
    const float* __restrict__ delta_W,
    const float* __restrict__ Bm,
    unsigned short* __restrict__ wbf)
{
    const int idx = blockIdx.x * 256 + threadIdx.x;  // float4 index, 12288 total
    const int row = idx >> 6;                        // 0..191
    const int c4  = (idx & 63) * 4;
    const float* src = (row < 64)  ? (sel_W   + (size_t)row * 256 + c4)
                     : (row < 128) ? (delta_W + (size_t)(row - 64) * 256 + c4)
                                   : (Bm      + (size_t)(row - 128) * 256 + c4);
    f32x4 v = *(const f32x4*)src;
    u16x4 pk;
    #pragma unroll
    for (int j = 0; j < 4; ++j) pk[j] = f2bf(v[j]);
    *(u16x4*)(wbf + (size_t)row * 256 + c4) = pk;
}

// ---------------------------------------------------------------------------
// Kernel 1: per (b, chunk of 64 tokens):
//   conv1d: ALL 18 x-row loads issued back-to-back (72 VGPR in flight,
//   continuous HBM delivery) -> bf16 xc tile in LDS (swizzled, 32 KiB);
//   W frags from global bf16 W with 3-deep rotating prefetch -> 96 MFMA ->
//   elementwise (native exp/log) -> ordered (P,S) chunk summary.
// Peak VGPR ~120 (cap 128 via launch_bounds, 4 blocks/CU).
// ---------------------------------------------------------------------------
__global__ __launch_bounds__(256, 4) void mamba_chunk_k(
    const float* __restrict__ x,
    const unsigned short* __restrict__ wbf,   // [192][256] bf16
    const float* __restrict__ sel_b,
    const float* __restrict__ selection_bias,
    const float* __restrict__ A_log,
    const float* __restrict__ delta_b,
    const float* __restrict__ conv_w,
    const float* __restrict__ conv_b,
    float* __restrict__ wsP,
    float* __restrict__ wsS)
{
    __shared__ char xc_base[Tq * 512];   // 64 rows x 512 B (bf16, swizzled)

    const int tid = threadIdx.x;
    const int b   = blockIdx.x >> 6;
    const int c   = blockIdx.x & 63;
    const int l0  = c * Tq;

    const int wv   = tid >> 6;
    const int lane = tid & 63;
    const int lr   = lane & 15;
    const int lg   = lane >> 4;

    // per-lane scan scalars (latency hides under conv+GEMM)
    const int   n   = wv * 16 + lr;
    const float Alg = A_log[n];
    const float sbc = sel_b[n] + selection_bias[n];
    const float dbv = delta_b[n];

    // W row base for this lane; prefetch kk=0 fragments before conv (L2 latency
    // hides under the whole conv phase)
    const unsigned short* wrow = wbf + (size_t)n * 256 + lg * 8;
    bf16x8 bfr[3];
    #pragma unroll
    for (int j = 0; j < 3; ++j)
        bfr[j] = *(const bf16x8*)(wrow + (size_t)j * 16384);

    // ---- Phase A: depthwise conv, 16 rows/wave, 18 loads batched up front ----
    const int d0 = lane * 4;

    float cw0[4], cw1[4], cw2[4], cbv[4];
    #pragma unroll
    for (int j = 0; j < 4; ++j) {
        cw0[j] = conv_w[(d0 + j) * 3 + 0];
        cw1[j] = conv_w[(d0 + j) * 3 + 1];
        cw2[j] = conv_w[(d0 + j) * 3 + 2];
        cbv[j] = conv_b[d0 + j];
    }

    const int tb = wv * 16;
    // rows tb..tb+15 need x rows (l0+tb-1) .. (l0+tb+16): 18 rows
    f32x4 xr[18];
    {
        const int g0 = l0 + tb - 1;
        const float* bp = x + ((long)b * Lq) * Dq + d0;
        #pragma unroll
        for (int i = 0; i < 18; ++i) {
            const int g = g0 + i;
            xr[i] = (f32x4){0.f, 0.f, 0.f, 0.f};
            if (g >= 0 && g < Lq)
                xr[i] = *(const f32x4*)(bp + (size_t)g * Dq);
        }
    }
    #pragma unroll
    for (int it = 0; it < 16; ++it) {
        const int row = tb + it;
        u16x4 pk;
        #pragma unroll
        for (int j = 0; j < 4; ++j) {
            float v = fmaf(cw0[j], xr[it][j],
                      fmaf(cw1[j], xr[it + 1][j],
                      fmaf(cw2[j], xr[it + 2][j], cbv[j])));
            pk[j] = f2bf(v);
        }
        *(u16x4*)(xc_base + row * 512 + ((d0 * 2) ^ ((row & 7) << 4))) = pk;
    }
    __syncthreads();

    // ---- Phase B: GEMM with 3-deep rotating W prefetch ----
    f32x4 acc[4][3];
    #pragma unroll
    for (int m = 0; m < 4; ++m)
        #pragma unroll
        for (int j = 0; j < 3; ++j)
            acc[m][j] = (f32x4){0.f, 0.f, 0.f, 0.f};

    #pragma unroll
    for (int kk = 0; kk < 8; ++kk) {
        bf16x8 cur[3];
        #pragma unroll
        for (int j = 0; j < 3; ++j) cur[j] = bfr[j];
        if (kk < 7) {
            #pragma unroll
            for (int j = 0; j < 3; ++j)
                bfr[j] = *(const bf16x8*)(wrow + (size_t)j * 16384 + (kk + 1) * 32);
        }
        const int cb = kk * 64 + lg * 16;
        #pragma unroll
        for (int m = 0; m < 4; ++m) {
            const int row = m * 16 + lr;
            bf16x8 af = *(const bf16x8*)(xc_base + row * 512 + (cb ^ ((row & 7) << 4)));
            #pragma unroll
            for (int j = 0; j < 3; ++j)
                acc[m][j] = __builtin_amdgcn_mfma_f32_16x16x32_bf16(af, cur[j], acc[m][j], 0, 0, 0);
        }
    }

    // ---- Phase C: elementwise (native transcendentals) + ordered (P,S) scan ----
    const float Av = -__expf(Alg);
    const float rD = 1.0f / (Av + 1e-8f);

    float Ptot = 1.0f, Stot = 0.0f;
    #pragma unroll
    for (int m = 0; m < 4; ++m) {
        float P = 1.0f, S = 0.0f;
        #pragma unroll
        for (int r = 0; r < 4; ++r) {
            const float sel = softplus_f(acc[m][0][r] + sbc);
            const float dl  = softplus_f(acc[m][1][r] + dbv);
            const float a   = __expf(dl * Av);
            const float bx  = (a - 1.0f) * rD * sel * acc[m][2][r];
            P *= a;
            S = fmaf(S, a, bx);
        }
        float Po = __shfl_xor(P, 16);
        float So = __shfl_xor(S, 16);
        if ((lg & 1) == 0) { S = fmaf(S, Po, So); P = P * Po; }
        else               { S = fmaf(So, P, S);  P = Po * P; }
        Po = __shfl_xor(P, 32);
        So = __shfl_xor(S, 32);
        if ((lg & 2) == 0) { S = fmaf(S, Po, So); P = P * Po; }
        else               { S = fmaf(So, P, S);  P = Po * P; }
        Stot = fmaf(Stot, P, S);
        Ptot *= P;
    }

    if (lg == 0) {
        const int o = (b * Cq + c) * Nq + n;
        wsP[o] = Ptot;
        wsS[o] = Stot;
    }
}

// ---------------------------------------------------------------------------
// Kernel 2: combine chunk summaries over time, then y = s@Cm^T + xc_last@Dm^T
// ---------------------------------------------------------------------------
__global__ __launch_bounds__(256) void mamba_final_k(
    const float* __restrict__ x,
    const float* __restrict__ conv_w,
    const float* __restrict__ conv_b,
    const float* __restrict__ Cm,
    const float* __restrict__ Dm,
    const float* __restrict__ wsP,
    const float* __restrict__ wsS,
    float* __restrict__ out)
{
    const int b   = blockIdx.x;
    const int tid = threadIdx.x;
    __shared__ float s_sh[Nq];
    __shared__ float xl_sh[Dq];

    {
        const int n   = tid >> 2;
        const int seg = tid & 3;
        float P = 1.0f, S = 0.0f;
        #pragma unroll
        for (int i = 0; i < 16; ++i) {
            const int c = seg * 16 + i;
            const float p  = wsP[(b * Cq + c) * Nq + n];
            const float s2 = wsS[(b * Cq + c) * Nq + n];
            S = fmaf(S, p, s2);
            P *= p;
        }
        float Po = __shfl_xor(P, 1);
        float So = __shfl_xor(S, 1);
        if ((seg & 1) == 0) { S = fmaf(S, Po, So); P = P * Po; }
        else                { S = fmaf(So, P, S);  P = Po * P; }
        Po = __shfl_xor(P, 2);
        So = __shfl_xor(S, 2);
        if ((seg & 2) == 0) { S = fmaf(S, Po, So); P = P * Po; }
        else                { S = fmaf(So, P, S);  P = Po * P; }
        if (seg == 0) s_sh[n] = S;
    }
    {
        const int d = tid;
        const float xm1 = x[((long)b * Lq + (Lq - 2)) * Dq + d];
        const float x0  = x[((long)b * Lq + (Lq - 1)) * Dq + d];
        xl_sh[d] = fmaf(conv_w[d * 3 + 0], xm1, fmaf(conv_w[d * 3 + 1], x0, conv_b[d]));
    }
    __syncthreads();

    const int o = tid;
    float accv = 0.0f;
    #pragma unroll 8
    for (int n = 0; n < Nq; ++n) accv = fmaf(s_sh[n], Cm[o * Nq + n], accv);
    #pragma unroll 8
    for (int d = 0; d < Dq; ++d) accv = fmaf(xl_sh[d], Dm[o * Dq + d], accv);
    out[b * Oq + o] = accv;
}

extern "C" void kernel_launch(void* const* d_in, const int* in_sizes, int n_in,
                              void* d_out, int out_size, void* d_ws, size_t ws_size,
                              hipStream_t stream)
{
    const float* x       = (const float*)d_in[0];
    const float* sel_W   = (const float*)d_in[1];
    const float* sel_b   = (const float*)d_in[2];
    const float* sel_bias= (const float*)d_in[3];
    const float* A_log   = (const float*)d_in[4];
    const float* Bm      = (const float*)d_in[5];
    const float* Cm      = (const float*)d_in[6];
    const float* Dm      = (const float*)d_in[7];
    const float* delta_W = (const float*)d_in[8];
    const float* delta_b = (const float*)d_in[9];
    const float* conv_w  = (const float*)d_in[10];
    const float* conv_b  = (const float*)d_in[11];
    float* out = (float*)d_out;

    float* wsP = (float*)d_ws;                               // 256 KB
    float* wsS = wsP + (size_t)Bq * Cq * Nq;                 // 256 KB
    unsigned short* wbf = (unsigned short*)(wsS + (size_t)Bq * Cq * Nq);  // 96 KB bf16

    prep_w_k<<<dim3(48), dim3(256), 0, stream>>>(sel_W, delta_W, Bm, wbf);
    mamba_chunk_k<<<dim3(Bq * Cq), dim3(256), 0, stream>>>(
        x, wbf, sel_b, sel_bias, A_log, delta_b, conv_w, conv_b, wsP, wsS);
    mamba_final_k<<<dim3(Bq), dim3(256), 0, stream>>>(
        x, conv_w, conv_b, Cm, Dm, wsP, wsS, out);
}